// Round 12
// baseline (208.120 us; speedup 1.0000x reference)
//
#include <hip/hip_runtime.h>

// GCN forward, 6-launch pipeline with hist/scatter split so gemm1 overlaps.
//   L1: bin (SINGLE-pass, bucket-major cells)  ||  wprep (Wt1, W2', b')
//   L2: hist per bucket (stream cells -> deg -> rowpair, inv)
//   L3: scatter per bucket (stream cells -> ebuf16)  ||  gemm1 (scaled h1t)
//   L4: agg1   agg1b[n][128] = relu(inv*sum h1t + b1) (4 slices x 2 XCDs)
//   L5: gemm2  h2t[n][64] = inv[i]*(agg1b@W2')[i]
//   L6: agg2 + log_softmax fused (8 lanes/node, uint4 rows)
// Cost model (r11): dur = kernels (~75) + ~43us fixed harness ws-fill
//                       + ~10-12us per launch gap. Attack kernels AND overlap.
// Lessons ledger:
//  r1: direct per-edge global scatter+atomics = 52us vs 34us bucketed build.
//  r3: unsliced gather FETCH = 8 XCD x whole array = L2 miss floor (2.5TB/s).
//  r6: slice planes sized to fit 4MB per-XCD L2 (FETCH 114->12MB); group-
//      parallel walks, NOT per-node shfl reduce trees (DS-pipe-bound, 99us).
//  r8: per-edge inv[src] gathers double L2 requests (agg1 43us) -> PRESCALE.
//  r10: grid.sync() ~100us+ on 8-XCD MI355X. Never megakernel.
//  r11: 6-launch all-fast == 5-launch with slow agg1 (192us both) -> gaps
//      ~10-12us each; split csr so gemm1 rides the scatter launch.

#define CIN  128
#define CHID 128
#define COUT 64
#define BCAP_SH 13           // per-bucket ebuf region: 8192 entries
#define BINCHUNK 2048
#define CELLCAP 32           // per-(bucket,chunk) cell cap (mean 8, P(>32)~1e-11)

typedef short v8s __attribute__((ext_vector_type(8)));
typedef float v4f __attribute__((ext_vector_type(4)));

static __device__ __forceinline__ unsigned short f2bf(float f) {
    unsigned int u = __float_as_uint(f);
    unsigned int r = (u + 0x7fffu + ((u >> 16) & 1u)) >> 16;  // RNE
    return (unsigned short)r;
}
static __device__ __forceinline__ float bflo(unsigned int u) {
    return __uint_as_float(u << 16);
}
static __device__ __forceinline__ float bfhi(unsigned int u) {
    return __uint_as_float(u & 0xffff0000u);
}
static __device__ __forceinline__ unsigned int pk2(float a, float b) {
    return (unsigned int)f2bf(a) | ((unsigned int)f2bf(b) << 16);
}

// ---------------- L1: single-pass bin (bucket-major cells) || wprep ----------
__global__ __launch_bounds__(256) void bin_wprep_kernel(
        const int* __restrict__ src, const int* __restrict__ dst,
        int* __restrict__ cnt,              // [nbkt][nchunk]
        unsigned int* __restrict__ binned,  // [nbkt][nchunk][CELLCAP]
        int E, int nchunk, int nbkt,
        const float* __restrict__ W1, const float* __restrict__ W2,
        const float* __restrict__ b2, const float* __restrict__ linW,
        const float* __restrict__ linb, unsigned short* __restrict__ Wt1,
        unsigned short* __restrict__ Wt2, float* __restrict__ bp) {
    int bb = blockIdx.x;
    int t = threadIdx.x;
    if (bb < nchunk) {
        __shared__ int cur[256];
        cur[t] = 0;
        __syncthreads();
        int e0 = bb * BINCHUNK;
        int e1 = e0 + BINCHUNK; if (e1 > E) e1 = E;
        for (int e = e0 + t; e < e1; e += 256) {
            int d = dst[e];
            int b = d >> 8;
            int pos = atomicAdd(&cur[b], 1);
            if (pos < CELLCAP)
                binned[((size_t)b * nchunk + bb) * CELLCAP + pos] =
                    (unsigned int)src[e] | (((unsigned int)d & 255u) << 16);
        }
        __syncthreads();
        if (t < nbkt) {
            int c = cur[t];
            cnt[(size_t)t * nchunk + bb] = c < CELLCAP ? c : CELLCAP;
        }
    } else {
        int wb = bb - nchunk;   // 0..128
        if (wb < CHID) {
            if (t < 128) {
                Wt1[wb * CIN + t] = f2bf(W1[t * CHID + wb]);
                if (t < COUT) {
                    float acc = 0.f;
#pragma unroll 8
                    for (int k = 0; k < COUT; ++k) {
                        float wsv = linW[k * COUT + t] + linW[(k + COUT) * COUT + t];
                        acc = fmaf(W2[wb * COUT + k], wsv, acc);
                    }
                    Wt2[t * CHID + wb] = f2bf(acc);
                }
            }
        } else if (t < COUT) {
            float acc = 0.f;
#pragma unroll 8
            for (int k = 0; k < COUT; ++k) {
                float wsv = linW[k * COUT + t] + linW[(k + COUT) * COUT + t];
                acc = fmaf(b2[k], wsv, acc);
            }
            bp[t] = acc + linb[t];
        }
    }
}

// ---------------- L2: hist per bucket -> rowpair, inv ----------------
__global__ __launch_bounds__(256) void hist_kernel(
        const unsigned int* __restrict__ binned, const int* __restrict__ cnt,
        int nchunk,
        int2* __restrict__ rowpair, float* __restrict__ inv, int n) {
    int b = blockIdx.x;
    int t = threadIdx.x;
    __shared__ int h[256];
    __shared__ int s2[256];
    __shared__ int ccnt[512];
    h[t] = 0;
    for (int c = t; c < nchunk; c += 256) ccnt[c] = cnt[(size_t)b * nchunk + c];
    __syncthreads();
    size_t base = (size_t)b * nchunk * CELLCAP;
    int tot = nchunk * CELLCAP;
    for (int idx = t; idx < tot; idx += 256) {
        int c = idx >> 5;              // CELLCAP = 32
        int i = idx & 31;
        if (i < ccnt[c])
            atomicAdd(&h[binned[base + idx] >> 16], 1);
    }
    __syncthreads();
    int myc = h[t];
    s2[t] = myc;
    __syncthreads();
    for (int off = 1; off < 256; off <<= 1) {
        int u = (t >= off) ? s2[t - off] : 0;
        __syncthreads();
        s2[t] += u;
        __syncthreads();
    }
    int ebase = b << BCAP_SH;
    int excl = s2[t] - myc;
    int node = (b << 8) + t;
    if (node < n) {
        rowpair[node] = make_int2(ebase + excl, ebase + excl + myc);
        inv[node] = rsqrtf((float)(myc + 1));  // +1: self-loop
    }
}

// ---------------- L3: scatter per bucket || gemm1 (scaled, slice-major) -----
__global__ __launch_bounds__(256) void scatter_gemm1_kernel(
        const unsigned int* __restrict__ binned, const int* __restrict__ cnt,
        int nchunk, int nbkt,
        const int2* __restrict__ rowpair, unsigned short* __restrict__ ebuf16,
        const float* __restrict__ x, const unsigned short* __restrict__ Wt1,
        const float* __restrict__ inv, unsigned short* __restrict__ h1t, int n) {
    int t = threadIdx.x;
    if ((int)blockIdx.x < nbkt) {
        // ---- scatter branch: bucket b
        int b = blockIdx.x;
        __shared__ int curs[256];
        __shared__ int ccnt[512];
        int node = (b << 8) + t;
        curs[t] = (node < n) ? rowpair[node].x : 0;
        for (int c = t; c < nchunk; c += 256) ccnt[c] = cnt[(size_t)b * nchunk + c];
        __syncthreads();
        size_t base = (size_t)b * nchunk * CELLCAP;
        int tot = nchunk * CELLCAP;
        for (int idx = t; idx < tot; idx += 256) {
            int c = idx >> 5;
            int i = idx & 31;
            if (i < ccnt[c]) {
                unsigned int e = binned[base + idx];
                int pos = atomicAdd(&curs[e >> 16], 1);
                ebuf16[pos] = (unsigned short)(e & 0xffffu);
            }
        }
    } else {
        // ---- gemm1 branch: 4 waves, scaled, slice-major h1t[4][n][32]
        int bid = blockIdx.x - nbkt;
        int lane = t & 63, wave = t >> 6;
        int quad = lane >> 4, r16 = lane & 15;
        int row0 = (bid * 4 + wave) * 16;
        if (row0 >= n) return;
        int arow = row0 + r16;
        if (arow >= n) arow = n - 1;
        size_t n32 = (size_t)n * 32;

        v4f acc[8];
#pragma unroll
        for (int c = 0; c < 8; ++c) acc[c] = (v4f){0.f, 0.f, 0.f, 0.f};
#pragma unroll
        for (int kc = 0; kc < 4; ++kc) {
            const float4* ap = (const float4*)(x + (size_t)arow * 128 + kc * 32 + quad * 8);
            float4 a0 = ap[0], a1 = ap[1];
            v8s af;
            af[0] = (short)f2bf(a0.x); af[1] = (short)f2bf(a0.y);
            af[2] = (short)f2bf(a0.z); af[3] = (short)f2bf(a0.w);
            af[4] = (short)f2bf(a1.x); af[5] = (short)f2bf(a1.y);
            af[6] = (short)f2bf(a1.z); af[7] = (short)f2bf(a1.w);
#pragma unroll
            for (int ct = 0; ct < 8; ++ct) {
                v8s bf = *(const v8s*)(Wt1 + (size_t)(ct * 16 + r16) * 128 + kc * 32 + quad * 8);
                acc[ct] = __builtin_amdgcn_mfma_f32_16x16x32_bf16(af, bf, acc[ct], 0, 0, 0);
            }
        }
        float4 iv = ((const float4*)(inv + row0))[quad];
#pragma unroll
        for (int ct = 0; ct < 8; ++ct) {
            int col = ct * 16 + r16;
            int pl = col >> 5, d = col & 31;
#pragma unroll
            for (int i = 0; i < 4; ++i) {
                int orow = row0 + quad * 4 + i;
                if (orow < n) {
                    float sc = (i == 0) ? iv.x : (i == 1) ? iv.y : (i == 2) ? iv.z : iv.w;
                    h1t[(size_t)pl * n32 + (size_t)orow * 32 + d] = f2bf(acc[ct][i] * sc);
                }
            }
        }
    }
}

// ---------------- L4: agg1, prescaled, 4 slices x 2 XCDs, ILP-4 walk --------
__global__ __launch_bounds__(256) void agg1_slice_kernel(
        const unsigned short* __restrict__ h1t,   // [4][n][32] bf16 PRESCALED
        const unsigned short* __restrict__ ebuf16,
        const int2* __restrict__ rowpair,
        const float* __restrict__ inv,
        const float* __restrict__ b1,
        unsigned int* __restrict__ agg1b,         // [n][64] uint (128 bf16)
        int n) {
    int b = blockIdx.x;
    int xcd = b & 7;
    int slice = xcd >> 1;
    int sub = xcd & 1;
    int grp = b >> 3;
    int wid = threadIdx.x >> 6;
    int lane = threadIdx.x & 63;
    int g = lane >> 3, s = lane & 7;
    int g8 = g << 3;
    const uint2* __restrict__ plane = (const uint2*)(h1t + (size_t)slice * n * 32);

    int node = (grp * 2 + sub) * 32 + wid * 8 + g;
    int cnode = node < n ? node : n - 1;
    int2 rp = rowpair[cnode];
    int beg = rp.x, len = rp.y - rp.x;
    int m = len < 64 ? len : 64;
    uint2 usl = plane[(size_t)cnode * 8 + s];     // self row (early, L2-hot)
    float wd = inv[cnode];
    float4 bv = ((const float4*)b1)[slice * 8 + s];

    int kmax = (m + 3) & ~3;
    float a0 = 0.f, a1 = 0.f, a2 = 0.f, a3 = 0.f;
    int eid = 0;
    for (int k = 0; k < kmax; k += 4) {           // 32 gathers in flight/wave
        if ((k & 7) == 0) eid = (int)ebuf16[beg + k + s];
        int i0 = __shfl(eid, g8 + (k & 7) + 0, 64);
        int i1 = __shfl(eid, g8 + (k & 7) + 1, 64);
        int i2 = __shfl(eid, g8 + (k & 7) + 2, 64);
        int i3 = __shfl(eid, g8 + (k & 7) + 3, 64);
        i0 = (k     < m) ? i0 : cnode;            // pads read own hot row
        i1 = (k + 1 < m) ? i1 : cnode;
        i2 = (k + 2 < m) ? i2 : cnode;
        i3 = (k + 3 < m) ? i3 : cnode;
        uint2 u0 = plane[(size_t)i0 * 8 + s];
        uint2 u1 = plane[(size_t)i1 * 8 + s];
        uint2 u2 = plane[(size_t)i2 * 8 + s];
        uint2 u3 = plane[(size_t)i3 * 8 + s];
        a0 += bflo(u0.x); a1 += bfhi(u0.x); a2 += bflo(u0.y); a3 += bfhi(u0.y);
        a0 += bflo(u1.x); a1 += bfhi(u1.x); a2 += bflo(u1.y); a3 += bfhi(u1.y);
        a0 += bflo(u2.x); a1 += bfhi(u2.x); a2 += bflo(u2.y); a3 += bfhi(u2.y);
        a0 += bflo(u3.x); a1 += bfhi(u3.x); a2 += bflo(u3.y); a3 += bfhi(u3.y);
    }
    if (len > 64) {                               // rare fallback (deg > 64)
        for (int k = 64; k < len; ++k) {
            int sid = (int)ebuf16[beg + k];
            uint2 uu = plane[(size_t)sid * 8 + s];
            a0 += bflo(uu.x); a1 += bfhi(uu.x); a2 += bflo(uu.y); a3 += bfhi(uu.y);
        }
    }
    float cc = 1.0f - (float)(kmax - m);          // pads added; want exactly 1 self
    a0 = fmaf(cc, bflo(usl.x), a0); a1 = fmaf(cc, bfhi(usl.x), a1);
    a2 = fmaf(cc, bflo(usl.y), a2); a3 = fmaf(cc, bfhi(usl.y), a3);
    float o0 = fmaxf(fmaf(wd, a0, bv.x), 0.f);
    float o1 = fmaxf(fmaf(wd, a1, bv.y), 0.f);
    float o2 = fmaxf(fmaf(wd, a2, bv.z), 0.f);
    float o3 = fmaxf(fmaf(wd, a3, bv.w), 0.f);
    if (node < n) {
        uint2 w; w.x = pk2(o0, o1); w.y = pk2(o2, o3);
        ((uint2*)agg1b)[(size_t)node * 32 + slice * 8 + s] = w;
    }
}

// ---------------- L5: gemm2, SCALED, node-major h2t[n][64] ------------------
__global__ __launch_bounds__(256) void gemm2_kernel(const unsigned short* __restrict__ A,
                                                    const unsigned short* __restrict__ Wt,
                                                    const float* __restrict__ inv,
                                                    unsigned short* __restrict__ h2t, int n) {
    int lane = threadIdx.x & 63;
    int wave = threadIdx.x >> 6;
    int quad = lane >> 4, r16 = lane & 15;
    int row0 = (blockIdx.x * 4 + wave) * 16;
    if (row0 >= n) return;
    int arow = row0 + r16;
    if (arow >= n) arow = n - 1;

    v4f acc[4];
#pragma unroll
    for (int c = 0; c < 4; ++c) acc[c] = (v4f){0.f, 0.f, 0.f, 0.f};
#pragma unroll
    for (int kc = 0; kc < 4; ++kc) {
        v8s af = *(const v8s*)(A + (size_t)arow * 128 + kc * 32 + quad * 8);
#pragma unroll
        for (int ct = 0; ct < 4; ++ct) {
            v8s bf = *(const v8s*)(Wt + (size_t)(ct * 16 + r16) * 128 + kc * 32 + quad * 8);
            acc[ct] = __builtin_amdgcn_mfma_f32_16x16x32_bf16(af, bf, acc[ct], 0, 0, 0);
        }
    }
    float4 iv = ((const float4*)(inv + row0))[quad];
#pragma unroll
    for (int ct = 0; ct < 4; ++ct) {
#pragma unroll
        for (int i = 0; i < 4; ++i) {
            int orow = row0 + quad * 4 + i;
            if (orow < n) {
                float sc = (i == 0) ? iv.x : (i == 1) ? iv.y : (i == 2) ? iv.z : iv.w;
                h2t[(size_t)orow * 64 + ct * 16 + r16] = f2bf(acc[ct][i] * sc);
            }
        }
    }
}

// ---------------- L6: agg2 + log_softmax fused (8 lanes/node, uint4) --------
__global__ __launch_bounds__(256) void agg2_softmax_kernel(
        const unsigned short* __restrict__ h2t,   // [n][64] bf16, prescaled
        const unsigned short* __restrict__ ebuf16,
        const int2* __restrict__ rowpair,
        const float* __restrict__ inv,
        const float* __restrict__ bp,
        float* __restrict__ outp, int n) {
    int wid = threadIdx.x >> 6;
    int lane = threadIdx.x & 63;
    int g = lane >> 3, s = lane & 7;
    int g8 = g << 3;
    int node = blockIdx.x * 32 + wid * 8 + g;
    int cnode = node < n ? node : n - 1;
    int2 rp = rowpair[cnode];
    int beg = rp.x, len = rp.y - rp.x;
    int m = len < 64 ? len : 64;
    const uint4* __restrict__ rows = (const uint4*)h2t;  // [n][8] uint4
    uint4 usl = rows[(size_t)cnode * 8 + s];
    float wd = inv[cnode];

    int kmax = (m + 1) & ~1;
    float a0 = 0.f, a1 = 0.f, a2 = 0.f, a3 = 0.f;
    float a4 = 0.f, a5 = 0.f, a6 = 0.f, a7 = 0.f;
    int eid = 0;
    for (int k = 0; k < kmax; k += 2) {
        if ((k & 7) == 0) eid = (int)ebuf16[beg + k + s];
        int sa = __shfl(eid, g8 + (k & 7), 64);
        int sb = __shfl(eid, g8 + (k & 7) + 1, 64);
        sa = (k     < m) ? sa : cnode;
        sb = (k + 1 < m) ? sb : cnode;
        uint4 ua = rows[(size_t)sa * 8 + s];
        uint4 ub = rows[(size_t)sb * 8 + s];
        a0 += bflo(ua.x); a1 += bfhi(ua.x); a2 += bflo(ua.y); a3 += bfhi(ua.y);
        a4 += bflo(ua.z); a5 += bfhi(ua.z); a6 += bflo(ua.w); a7 += bfhi(ua.w);
        a0 += bflo(ub.x); a1 += bfhi(ub.x); a2 += bflo(ub.y); a3 += bfhi(ub.y);
        a4 += bflo(ub.z); a5 += bfhi(ub.z); a6 += bflo(ub.w); a7 += bfhi(ub.w);
    }
    if (len > 64) {
        for (int k = 64; k < len; ++k) {
            int sid = (int)ebuf16[beg + k];
            uint4 u = rows[(size_t)sid * 8 + s];
            a0 += bflo(u.x); a1 += bfhi(u.x); a2 += bflo(u.y); a3 += bfhi(u.y);
            a4 += bflo(u.z); a5 += bfhi(u.z); a6 += bflo(u.w); a7 += bfhi(u.w);
        }
    }
    float c2 = 1.0f - (float)(kmax - m);
    a0 = fmaf(c2, bflo(usl.x), a0); a1 = fmaf(c2, bfhi(usl.x), a1);
    a2 = fmaf(c2, bflo(usl.y), a2); a3 = fmaf(c2, bfhi(usl.y), a3);
    a4 = fmaf(c2, bflo(usl.z), a4); a5 = fmaf(c2, bfhi(usl.z), a5);
    a6 = fmaf(c2, bflo(usl.w), a6); a7 = fmaf(c2, bfhi(usl.w), a7);
    float4 bpa = ((const float4*)bp)[s * 2];
    float4 bpb = ((const float4*)bp)[s * 2 + 1];
    float f0 = fmaf(wd, a0, bpa.x), f1 = fmaf(wd, a1, bpa.y);
    float f2 = fmaf(wd, a2, bpa.z), f3 = fmaf(wd, a3, bpa.w);
    float f4 = fmaf(wd, a4, bpb.x), f5 = fmaf(wd, a5, bpb.y);
    float f6 = fmaf(wd, a6, bpb.z), f7 = fmaf(wd, a7, bpb.w);
    float mx = fmaxf(fmaxf(fmaxf(f0, f1), fmaxf(f2, f3)),
                     fmaxf(fmaxf(f4, f5), fmaxf(f6, f7)));
    mx = fmaxf(mx, __shfl_xor(mx, 1, 64));
    mx = fmaxf(mx, __shfl_xor(mx, 2, 64));
    mx = fmaxf(mx, __shfl_xor(mx, 4, 64));
    float sum = expf(f0 - mx) + expf(f1 - mx) + expf(f2 - mx) + expf(f3 - mx)
              + expf(f4 - mx) + expf(f5 - mx) + expf(f6 - mx) + expf(f7 - mx);
    sum += __shfl_xor(sum, 1, 64);
    sum += __shfl_xor(sum, 2, 64);
    sum += __shfl_xor(sum, 4, 64);
    float ls = mx + logf(sum);
    if (node < n) {
        ((float4*)outp)[(size_t)node * 16 + s * 2] =
            make_float4(f0 - ls, f1 - ls, f2 - ls, f3 - ls);
        ((float4*)outp)[(size_t)node * 16 + s * 2 + 1] =
            make_float4(f4 - ls, f5 - ls, f6 - ls, f7 - ls);
    }
}

static inline size_t align16(size_t x) { return (x + 15) & ~(size_t)15; }

extern "C" void kernel_launch(void* const* d_in, const int* in_sizes, int n_in,
                              void* d_out, int out_size, void* d_ws, size_t ws_size,
                              hipStream_t stream) {
    const float* x    = (const float*)d_in[0];
    const int*   eidx = (const int*)d_in[1];
    const float* W1   = (const float*)d_in[2];
    const float* b1   = (const float*)d_in[3];
    const float* W2   = (const float*)d_in[4];
    const float* b2   = (const float*)d_in[5];
    const float* linW = (const float*)d_in[6];
    const float* linb = (const float*)d_in[7];
    float* out = (float*)d_out;

    const int n = in_sizes[0] / CIN;   // 50000
    const int E = in_sizes[1] / 2;     // 800000
    const int* src = eidx;
    const int* dst = eidx + E;
    const int NBKT = (n + 255) >> 8;               // 196
    const int NCHUNK = (E + BINCHUNK - 1) / BINCHUNK;  // 391 (<= 512)

    // ---- workspace carve-up
    char* ws = (char*)d_ws;
    size_t off = 0;
    int2*  rowpair = (int2*)(ws + off);  off = align16(off + (size_t)n * 8);
    float* inv     = (float*)(ws + off); off = align16(off + (size_t)n * 4);
    int*   cnt     = (int*)(ws + off);   off = align16(off + (size_t)NBKT * NCHUNK * 4);
    unsigned short* Wt1 = (unsigned short*)(ws + off); off = align16(off + (size_t)CHID * CIN * 2);
    unsigned short* Wt2 = (unsigned short*)(ws + off); off = align16(off + (size_t)COUT * CHID * 2);
    float* bp      = (float*)(ws + off); off = align16(off + (size_t)COUT * 4);
    unsigned int* binned = (unsigned int*)(ws + off);
    off = align16(off + (size_t)NBKT * NCHUNK * CELLCAP * 4);
    unsigned short* ebuf16 = (unsigned short*)(ws + off);
    off = align16(off + (size_t)NBKT * (1 << BCAP_SH) * 2);
    unsigned short* h1t   = (unsigned short*)(ws + off); off = align16(off + (size_t)n * CHID * 2);
    unsigned int*   agg1b = (unsigned int*)(ws + off);   off = align16(off + (size_t)n * CHID * 2);
    unsigned short* h2t   = (unsigned short*)(ws + off); off = align16(off + (size_t)n * COUT * 2);

    // ---- L1: bin (single-pass) || wprep
    bin_wprep_kernel<<<NCHUNK + CHID + 1, 256, 0, stream>>>(
        src, dst, cnt, binned, E, NCHUNK, NBKT, W1, W2, b2, linW, linb, Wt1, Wt2, bp);

    // ---- L2: hist -> rowpair, inv
    hist_kernel<<<NBKT, 256, 0, stream>>>(binned, cnt, NCHUNK, rowpair, inv, n);

    // ---- L3: scatter || gemm1 (scaled)
    const int G1B = (n + 63) / 64;
    scatter_gemm1_kernel<<<NBKT + G1B, 256, 0, stream>>>(
        binned, cnt, NCHUNK, NBKT, rowpair, ebuf16, x, Wt1, inv, h1t, n);

    // ---- L4: agg1 (4 slices x 2 XCD subranges)
    agg1_slice_kernel<<<G1B * 8, 256, 0, stream>>>(h1t, ebuf16, rowpair, inv, b1, agg1b, n);

    // ---- L5: gemm2 (scaled, node-major)
    gemm2_kernel<<<G1B, 256, 0, stream>>>((const unsigned short*)agg1b, Wt2, inv, h2t, n);

    // ---- L6: agg2 + log_softmax
    agg2_softmax_kernel<<<(n + 31) / 32, 256, 0, stream>>>(h2t, ebuf16, rowpair, inv, bp, out, n);
}

// Round 13
// 183.125 us; speedup vs baseline: 1.1365x; 1.1365x over previous
//
#include <hip/hip_runtime.h>

// GCN forward, 6-launch pipeline, hist/scatter split, CHUNK-major cells.
//   L1: bin (single-pass LDS-cursor scatter, chunk-major cells) || wprep
//   L2: hist per bucket (cells -> deg -> rowpair, inv)
//   L3: scatter per bucket (cells -> ebuf16)  ||  gemm1 (SCALED h1t)
//   L4: agg1   agg1b[n][128] = relu(inv*sum h1t + b1) (4 slices x 2 XCDs)
//   L5: gemm2  h2t[n][64] = inv[i]*(agg1b@W2')[i]
//   L6: agg2 + log_softmax fused (8 lanes/node, uint4 rows)
// Cost model (r11): dur = kernels (~75) + fixed harness overhead
//                       + ~10-12us per launch gap.
// Lessons ledger:
//  r1:  direct per-edge global scatter+atomics = 52us vs 34us bucketed build.
//  r3:  unsliced gather FETCH = 8 XCD x whole array = L2 miss floor (2.5TB/s).
//  r6:  slice planes sized to fit 4MB per-XCD L2 (FETCH 114->12MB); group-
//       parallel walks, NOT per-node shfl reduce trees (DS-pipe-bound, 99us).
//  r8:  per-edge inv[src] gathers double L2 requests (agg1 43us) -> PRESCALE.
//  r10: grid.sync() ~100us+ on 8-XCD MI355X. Never megakernel.
//  r11: 6-launch all-fast == 5-launch with slow agg1 (192us both).
//  r12: BUCKET-major cells re-created r1's scattered writes (208us).
//       Chunk-major cell writes (one 32KB region per chunk block) are required.

#define CIN  128
#define CHID 128
#define COUT 64
#define BCAP_SH 13           // per-bucket ebuf region: 8192 entries
#define BINCHUNK 2048
#define CELLCAP 32           // per-(chunk,bucket) cell cap (mean 8, P(>32)~1e-11)

typedef short v8s __attribute__((ext_vector_type(8)));
typedef float v4f __attribute__((ext_vector_type(4)));

static __device__ __forceinline__ unsigned short f2bf(float f) {
    unsigned int u = __float_as_uint(f);
    unsigned int r = (u + 0x7fffu + ((u >> 16) & 1u)) >> 16;  // RNE
    return (unsigned short)r;
}
static __device__ __forceinline__ float bflo(unsigned int u) {
    return __uint_as_float(u << 16);
}
static __device__ __forceinline__ float bfhi(unsigned int u) {
    return __uint_as_float(u & 0xffff0000u);
}
static __device__ __forceinline__ unsigned int pk2(float a, float b) {
    return (unsigned int)f2bf(a) | ((unsigned int)f2bf(b) << 16);
}

// ---------------- L1: single-pass bin (CHUNK-major cells) || wprep ----------
__global__ __launch_bounds__(256) void bin_wprep_kernel(
        const int* __restrict__ src, const int* __restrict__ dst,
        int* __restrict__ cnt,              // [nchunk][256]
        unsigned int* __restrict__ binned,  // [nchunk][256][CELLCAP]
        int E, int nchunk,
        const float* __restrict__ W1, const float* __restrict__ W2,
        const float* __restrict__ b2, const float* __restrict__ linW,
        const float* __restrict__ linb, unsigned short* __restrict__ Wt1,
        unsigned short* __restrict__ Wt2, float* __restrict__ bp) {
    int bb = blockIdx.x;
    int t = threadIdx.x;
    if (bb < nchunk) {
        __shared__ int cur[256];
        cur[t] = 0;
        __syncthreads();
        int e0 = bb * BINCHUNK;
        int e1 = e0 + BINCHUNK; if (e1 > E) e1 = E;
        for (int e = e0 + t; e < e1; e += 256) {
            int d = dst[e];
            int b = d >> 8;
            int pos = atomicAdd(&cur[b], 1);
            if (pos < CELLCAP)
                binned[((size_t)(bb * 256 + b)) * CELLCAP + pos] =
                    (unsigned int)src[e] | (((unsigned int)d & 255u) << 16);
        }
        __syncthreads();
        int c = cur[t];
        cnt[bb * 256 + t] = c < CELLCAP ? c : CELLCAP;
    } else {
        int wb = bb - nchunk;   // 0..128
        if (wb < CHID) {
            if (t < 128) {
                Wt1[wb * CIN + t] = f2bf(W1[t * CHID + wb]);
                if (t < COUT) {
                    float acc = 0.f;
#pragma unroll 8
                    for (int k = 0; k < COUT; ++k) {
                        float wsv = linW[k * COUT + t] + linW[(k + COUT) * COUT + t];
                        acc = fmaf(W2[wb * COUT + k], wsv, acc);
                    }
                    Wt2[t * CHID + wb] = f2bf(acc);
                }
            }
        } else if (t < COUT) {
            float acc = 0.f;
#pragma unroll 8
            for (int k = 0; k < COUT; ++k) {
                float wsv = linW[k * COUT + t] + linW[(k + COUT) * COUT + t];
                acc = fmaf(b2[k], wsv, acc);
            }
            bp[t] = acc + linb[t];
        }
    }
}

// ---------------- L2: hist per bucket -> rowpair, inv ----------------
// 512 threads; thread t handles chunk t (nchunk <= 512): reads its cell
// (<= 128B contiguous) and LDS-atomics the per-dst histogram.
__global__ __launch_bounds__(512) void hist_kernel(
        const unsigned int* __restrict__ binned, const int* __restrict__ cnt,
        int nchunk,
        int2* __restrict__ rowpair, float* __restrict__ inv, int n) {
    int b = blockIdx.x;
    int t = threadIdx.x;
    __shared__ int h[256];
    __shared__ int s2[256];
    if (t < 256) h[t] = 0;
    __syncthreads();
    if (t < nchunk) {
        int cc = cnt[t * 256 + b];
        const unsigned int* cell = binned + ((size_t)(t * 256 + b)) * CELLCAP;
        for (int i = 0; i < cc; ++i)
            atomicAdd(&h[cell[i] >> 16], 1);
    }
    __syncthreads();
    int myc = (t < 256) ? h[t] : 0;
    if (t < 256) s2[t] = myc;
    __syncthreads();
    for (int off = 1; off < 256; off <<= 1) {
        int u = (t >= off && t < 256) ? s2[t - off] : 0;
        __syncthreads();
        if (t < 256) s2[t] += u;
        __syncthreads();
    }
    if (t < 256) {
        int ebase = b << BCAP_SH;
        int excl = s2[t] - myc;
        int node = (b << 8) + t;
        if (node < n) {
            rowpair[node] = make_int2(ebase + excl, ebase + excl + myc);
            inv[node] = rsqrtf((float)(myc + 1));  // +1: self-loop
        }
    }
}

// ---------------- L3: scatter per bucket || gemm1 (SCALED, slice-major) -----
__global__ __launch_bounds__(256) void scatter_gemm1_kernel(
        const unsigned int* __restrict__ binned, const int* __restrict__ cnt,
        int nchunk, int nbkt,
        const int2* __restrict__ rowpair, unsigned short* __restrict__ ebuf16,
        const float* __restrict__ x, const unsigned short* __restrict__ Wt1,
        const float* __restrict__ inv, unsigned short* __restrict__ h1t, int n) {
    int t = threadIdx.x;
    if ((int)blockIdx.x < nbkt) {
        // ---- scatter branch: bucket b (cursor = rowpair.x in LDS)
        int b = blockIdx.x;
        __shared__ int curs[256];
        int node = (b << 8) + t;
        curs[t] = (node < n) ? rowpair[node].x : 0;
        __syncthreads();
        for (int c = t; c < nchunk; c += 256) {
            int cc = cnt[c * 256 + b];
            const unsigned int* cell = binned + ((size_t)(c * 256 + b)) * CELLCAP;
            for (int i = 0; i < cc; ++i) {
                unsigned int e = cell[i];
                int pos = atomicAdd(&curs[e >> 16], 1);
                ebuf16[pos] = (unsigned short)(e & 0xffffu);
            }
        }
    } else {
        // ---- gemm1 branch: 4 waves, SCALED, slice-major h1t[4][n][32]
        int bid = blockIdx.x - nbkt;
        int lane = t & 63, wave = t >> 6;
        int quad = lane >> 4, r16 = lane & 15;
        int row0 = (bid * 4 + wave) * 16;
        if (row0 >= n) return;
        int arow = row0 + r16;
        if (arow >= n) arow = n - 1;
        size_t n32 = (size_t)n * 32;

        v4f acc[8];
#pragma unroll
        for (int c = 0; c < 8; ++c) acc[c] = (v4f){0.f, 0.f, 0.f, 0.f};
#pragma unroll
        for (int kc = 0; kc < 4; ++kc) {
            const float4* ap = (const float4*)(x + (size_t)arow * 128 + kc * 32 + quad * 8);
            float4 a0 = ap[0], a1 = ap[1];
            v8s af;
            af[0] = (short)f2bf(a0.x); af[1] = (short)f2bf(a0.y);
            af[2] = (short)f2bf(a0.z); af[3] = (short)f2bf(a0.w);
            af[4] = (short)f2bf(a1.x); af[5] = (short)f2bf(a1.y);
            af[6] = (short)f2bf(a1.z); af[7] = (short)f2bf(a1.w);
#pragma unroll
            for (int ct = 0; ct < 8; ++ct) {
                v8s bf = *(const v8s*)(Wt1 + (size_t)(ct * 16 + r16) * 128 + kc * 32 + quad * 8);
                acc[ct] = __builtin_amdgcn_mfma_f32_16x16x32_bf16(af, bf, acc[ct], 0, 0, 0);
            }
        }
        float4 iv = ((const float4*)(inv + row0))[quad];
#pragma unroll
        for (int ct = 0; ct < 8; ++ct) {
            int col = ct * 16 + r16;
            int pl = col >> 5, d = col & 31;
#pragma unroll
            for (int i = 0; i < 4; ++i) {
                int orow = row0 + quad * 4 + i;
                if (orow < n) {
                    float sc = (i == 0) ? iv.x : (i == 1) ? iv.y : (i == 2) ? iv.z : iv.w;
                    h1t[(size_t)pl * n32 + (size_t)orow * 32 + d] = f2bf(acc[ct][i] * sc);
                }
            }
        }
    }
}

// ---------------- L4: agg1, prescaled, 4 slices x 2 XCDs, ILP-4 walk --------
__global__ __launch_bounds__(256) void agg1_slice_kernel(
        const unsigned short* __restrict__ h1t,   // [4][n][32] bf16 PRESCALED
        const unsigned short* __restrict__ ebuf16,
        const int2* __restrict__ rowpair,
        const float* __restrict__ inv,
        const float* __restrict__ b1,
        unsigned int* __restrict__ agg1b,         // [n][64] uint (128 bf16)
        int n) {
    int b = blockIdx.x;
    int xcd = b & 7;
    int slice = xcd >> 1;
    int sub = xcd & 1;
    int grp = b >> 3;
    int wid = threadIdx.x >> 6;
    int lane = threadIdx.x & 63;
    int g = lane >> 3, s = lane & 7;
    int g8 = g << 3;
    const uint2* __restrict__ plane = (const uint2*)(h1t + (size_t)slice * n * 32);

    int node = (grp * 2 + sub) * 32 + wid * 8 + g;
    int cnode = node < n ? node : n - 1;
    int2 rp = rowpair[cnode];
    int beg = rp.x, len = rp.y - rp.x;
    int m = len < 64 ? len : 64;
    uint2 usl = plane[(size_t)cnode * 8 + s];     // self row (early, L2-hot)
    float wd = inv[cnode];
    float4 bv = ((const float4*)b1)[slice * 8 + s];

    int kmax = (m + 3) & ~3;
    float a0 = 0.f, a1 = 0.f, a2 = 0.f, a3 = 0.f;
    int eid = 0;
    for (int k = 0; k < kmax; k += 4) {           // 32 gathers in flight/wave
        if ((k & 7) == 0) eid = (int)ebuf16[beg + k + s];
        int i0 = __shfl(eid, g8 + (k & 7) + 0, 64);
        int i1 = __shfl(eid, g8 + (k & 7) + 1, 64);
        int i2 = __shfl(eid, g8 + (k & 7) + 2, 64);
        int i3 = __shfl(eid, g8 + (k & 7) + 3, 64);
        i0 = (k     < m) ? i0 : cnode;            // pads read own hot row
        i1 = (k + 1 < m) ? i1 : cnode;
        i2 = (k + 2 < m) ? i2 : cnode;
        i3 = (k + 3 < m) ? i3 : cnode;
        uint2 u0 = plane[(size_t)i0 * 8 + s];
        uint2 u1 = plane[(size_t)i1 * 8 + s];
        uint2 u2 = plane[(size_t)i2 * 8 + s];
        uint2 u3 = plane[(size_t)i3 * 8 + s];
        a0 += bflo(u0.x); a1 += bfhi(u0.x); a2 += bflo(u0.y); a3 += bfhi(u0.y);
        a0 += bflo(u1.x); a1 += bfhi(u1.x); a2 += bflo(u1.y); a3 += bfhi(u1.y);
        a0 += bflo(u2.x); a1 += bfhi(u2.x); a2 += bflo(u2.y); a3 += bfhi(u2.y);
        a0 += bflo(u3.x); a1 += bfhi(u3.x); a2 += bflo(u3.y); a3 += bfhi(u3.y);
    }
    if (len > 64) {                               // rare fallback (deg > 64)
        for (int k = 64; k < len; ++k) {
            int sid = (int)ebuf16[beg + k];
            uint2 uu = plane[(size_t)sid * 8 + s];
            a0 += bflo(uu.x); a1 += bfhi(uu.x); a2 += bflo(uu.y); a3 += bfhi(uu.y);
        }
    }
    float cc = 1.0f - (float)(kmax - m);          // pads added; want exactly 1 self
    a0 = fmaf(cc, bflo(usl.x), a0); a1 = fmaf(cc, bfhi(usl.x), a1);
    a2 = fmaf(cc, bflo(usl.y), a2); a3 = fmaf(cc, bfhi(usl.y), a3);
    float o0 = fmaxf(fmaf(wd, a0, bv.x), 0.f);
    float o1 = fmaxf(fmaf(wd, a1, bv.y), 0.f);
    float o2 = fmaxf(fmaf(wd, a2, bv.z), 0.f);
    float o3 = fmaxf(fmaf(wd, a3, bv.w), 0.f);
    if (node < n) {
        uint2 w; w.x = pk2(o0, o1); w.y = pk2(o2, o3);
        ((uint2*)agg1b)[(size_t)node * 32 + slice * 8 + s] = w;
    }
}

// ---------------- L5: gemm2, SCALED, node-major h2t[n][64] ------------------
__global__ __launch_bounds__(256) void gemm2_kernel(const unsigned short* __restrict__ A,
                                                    const unsigned short* __restrict__ Wt,
                                                    const float* __restrict__ inv,
                                                    unsigned short* __restrict__ h2t, int n) {
    int lane = threadIdx.x & 63;
    int wave = threadIdx.x >> 6;
    int quad = lane >> 4, r16 = lane & 15;
    int row0 = (blockIdx.x * 4 + wave) * 16;
    if (row0 >= n) return;
    int arow = row0 + r16;
    if (arow >= n) arow = n - 1;

    v4f acc[4];
#pragma unroll
    for (int c = 0; c < 4; ++c) acc[c] = (v4f){0.f, 0.f, 0.f, 0.f};
#pragma unroll
    for (int kc = 0; kc < 4; ++kc) {
        v8s af = *(const v8s*)(A + (size_t)arow * 128 + kc * 32 + quad * 8);
#pragma unroll
        for (int ct = 0; ct < 4; ++ct) {
            v8s bf = *(const v8s*)(Wt + (size_t)(ct * 16 + r16) * 128 + kc * 32 + quad * 8);
            acc[ct] = __builtin_amdgcn_mfma_f32_16x16x32_bf16(af, bf, acc[ct], 0, 0, 0);
        }
    }
    float4 iv = ((const float4*)(inv + row0))[quad];
#pragma unroll
    for (int ct = 0; ct < 4; ++ct) {
#pragma unroll
        for (int i = 0; i < 4; ++i) {
            int orow = row0 + quad * 4 + i;
            if (orow < n) {
                float sc = (i == 0) ? iv.x : (i == 1) ? iv.y : (i == 2) ? iv.z : iv.w;
                h2t[(size_t)orow * 64 + ct * 16 + r16] = f2bf(acc[ct][i] * sc);
            }
        }
    }
}

// ---------------- L6: agg2 + log_softmax fused (8 lanes/node, uint4) --------
__global__ __launch_bounds__(256) void agg2_softmax_kernel(
        const unsigned short* __restrict__ h2t,   // [n][64] bf16, prescaled
        const unsigned short* __restrict__ ebuf16,
        const int2* __restrict__ rowpair,
        const float* __restrict__ inv,
        const float* __restrict__ bp,
        float* __restrict__ outp, int n) {
    int wid = threadIdx.x >> 6;
    int lane = threadIdx.x & 63;
    int g = lane >> 3, s = lane & 7;
    int g8 = g << 3;
    int node = blockIdx.x * 32 + wid * 8 + g;
    int cnode = node < n ? node : n - 1;
    int2 rp = rowpair[cnode];
    int beg = rp.x, len = rp.y - rp.x;
    int m = len < 64 ? len : 64;
    const uint4* __restrict__ rows = (const uint4*)h2t;  // [n][8] uint4
    uint4 usl = rows[(size_t)cnode * 8 + s];
    float wd = inv[cnode];

    int kmax = (m + 1) & ~1;
    float a0 = 0.f, a1 = 0.f, a2 = 0.f, a3 = 0.f;
    float a4 = 0.f, a5 = 0.f, a6 = 0.f, a7 = 0.f;
    int eid = 0;
    for (int k = 0; k < kmax; k += 2) {
        if ((k & 7) == 0) eid = (int)ebuf16[beg + k + s];
        int sa = __shfl(eid, g8 + (k & 7), 64);
        int sb = __shfl(eid, g8 + (k & 7) + 1, 64);
        sa = (k     < m) ? sa : cnode;
        sb = (k + 1 < m) ? sb : cnode;
        uint4 ua = rows[(size_t)sa * 8 + s];
        uint4 ub = rows[(size_t)sb * 8 + s];
        a0 += bflo(ua.x); a1 += bfhi(ua.x); a2 += bflo(ua.y); a3 += bfhi(ua.y);
        a4 += bflo(ua.z); a5 += bfhi(ua.z); a6 += bflo(ua.w); a7 += bfhi(ua.w);
        a0 += bflo(ub.x); a1 += bfhi(ub.x); a2 += bflo(ub.y); a3 += bfhi(ub.y);
        a4 += bflo(ub.z); a5 += bfhi(ub.z); a6 += bflo(ub.w); a7 += bfhi(ub.w);
    }
    if (len > 64) {
        for (int k = 64; k < len; ++k) {
            int sid = (int)ebuf16[beg + k];
            uint4 u = rows[(size_t)sid * 8 + s];
            a0 += bflo(u.x); a1 += bfhi(u.x); a2 += bflo(u.y); a3 += bfhi(u.y);
            a4 += bflo(u.z); a5 += bfhi(u.z); a6 += bflo(u.w); a7 += bfhi(u.w);
        }
    }
    float c2 = 1.0f - (float)(kmax - m);
    a0 = fmaf(c2, bflo(usl.x), a0); a1 = fmaf(c2, bfhi(usl.x), a1);
    a2 = fmaf(c2, bflo(usl.y), a2); a3 = fmaf(c2, bfhi(usl.y), a3);
    a4 = fmaf(c2, bflo(usl.z), a4); a5 = fmaf(c2, bfhi(usl.z), a5);
    a6 = fmaf(c2, bflo(usl.w), a6); a7 = fmaf(c2, bfhi(usl.w), a7);
    float4 bpa = ((const float4*)bp)[s * 2];
    float4 bpb = ((const float4*)bp)[s * 2 + 1];
    float f0 = fmaf(wd, a0, bpa.x), f1 = fmaf(wd, a1, bpa.y);
    float f2 = fmaf(wd, a2, bpa.z), f3 = fmaf(wd, a3, bpa.w);
    float f4 = fmaf(wd, a4, bpb.x), f5 = fmaf(wd, a5, bpb.y);
    float f6 = fmaf(wd, a6, bpb.z), f7 = fmaf(wd, a7, bpb.w);
    float mx = fmaxf(fmaxf(fmaxf(f0, f1), fmaxf(f2, f3)),
                     fmaxf(fmaxf(f4, f5), fmaxf(f6, f7)));
    mx = fmaxf(mx, __shfl_xor(mx, 1, 64));
    mx = fmaxf(mx, __shfl_xor(mx, 2, 64));
    mx = fmaxf(mx, __shfl_xor(mx, 4, 64));
    float sum = expf(f0 - mx) + expf(f1 - mx) + expf(f2 - mx) + expf(f3 - mx)
              + expf(f4 - mx) + expf(f5 - mx) + expf(f6 - mx) + expf(f7 - mx);
    sum += __shfl_xor(sum, 1, 64);
    sum += __shfl_xor(sum, 2, 64);
    sum += __shfl_xor(sum, 4, 64);
    float ls = mx + logf(sum);
    if (node < n) {
        ((float4*)outp)[(size_t)node * 16 + s * 2] =
            make_float4(f0 - ls, f1 - ls, f2 - ls, f3 - ls);
        ((float4*)outp)[(size_t)node * 16 + s * 2 + 1] =
            make_float4(f4 - ls, f5 - ls, f6 - ls, f7 - ls);
    }
}

static inline size_t align16(size_t x) { return (x + 15) & ~(size_t)15; }

extern "C" void kernel_launch(void* const* d_in, const int* in_sizes, int n_in,
                              void* d_out, int out_size, void* d_ws, size_t ws_size,
                              hipStream_t stream) {
    const float* x    = (const float*)d_in[0];
    const int*   eidx = (const int*)d_in[1];
    const float* W1   = (const float*)d_in[2];
    const float* b1   = (const float*)d_in[3];
    const float* W2   = (const float*)d_in[4];
    const float* b2   = (const float*)d_in[5];
    const float* linW = (const float*)d_in[6];
    const float* linb = (const float*)d_in[7];
    float* out = (float*)d_out;

    const int n = in_sizes[0] / CIN;   // 50000
    const int E = in_sizes[1] / 2;     // 800000
    const int* src = eidx;
    const int* dst = eidx + E;
    const int NBKT = (n + 255) >> 8;               // 196
    const int NCHUNK = (E + BINCHUNK - 1) / BINCHUNK;  // 391 (<= 512)

    // ---- workspace carve-up
    char* ws = (char*)d_ws;
    size_t off = 0;
    int2*  rowpair = (int2*)(ws + off);  off = align16(off + (size_t)n * 8);
    float* inv     = (float*)(ws + off); off = align16(off + (size_t)n * 4);
    int*   cnt     = (int*)(ws + off);   off = align16(off + (size_t)NCHUNK * 256 * 4);
    unsigned short* Wt1 = (unsigned short*)(ws + off); off = align16(off + (size_t)CHID * CIN * 2);
    unsigned short* Wt2 = (unsigned short*)(ws + off); off = align16(off + (size_t)COUT * CHID * 2);
    float* bp      = (float*)(ws + off); off = align16(off + (size_t)COUT * 4);
    unsigned int* binned = (unsigned int*)(ws + off);
    off = align16(off + (size_t)NCHUNK * 256 * CELLCAP * 4);
    unsigned short* ebuf16 = (unsigned short*)(ws + off);
    off = align16(off + (size_t)NBKT * (1 << BCAP_SH) * 2);
    unsigned short* h1t   = (unsigned short*)(ws + off); off = align16(off + (size_t)n * CHID * 2);
    unsigned int*   agg1b = (unsigned int*)(ws + off);   off = align16(off + (size_t)n * CHID * 2);
    unsigned short* h2t   = (unsigned short*)(ws + off); off = align16(off + (size_t)n * COUT * 2);

    // ---- L1: bin (single-pass, chunk-major) || wprep
    bin_wprep_kernel<<<NCHUNK + CHID + 1, 256, 0, stream>>>(
        src, dst, cnt, binned, E, NCHUNK, W1, W2, b2, linW, linb, Wt1, Wt2, bp);

    // ---- L2: hist -> rowpair, inv
    hist_kernel<<<NBKT, 512, 0, stream>>>(binned, cnt, NCHUNK, rowpair, inv, n);

    // ---- L3: scatter || gemm1 (scaled)
    const int G1B = (n + 63) / 64;
    scatter_gemm1_kernel<<<NBKT + G1B, 256, 0, stream>>>(
        binned, cnt, NCHUNK, NBKT, rowpair, ebuf16, x, Wt1, inv, h1t, n);

    // ---- L4: agg1 (4 slices x 2 XCD subranges)
    agg1_slice_kernel<<<G1B * 8, 256, 0, stream>>>(h1t, ebuf16, rowpair, inv, b1, agg1b, n);

    // ---- L5: gemm2 (scaled, node-major)
    gemm2_kernel<<<G1B, 256, 0, stream>>>((const unsigned short*)agg1b, Wt2, inv, h2t, n);

    // ---- L6: agg2 + log_softmax
    agg2_softmax_kernel<<<(n + 31) / 32, 256, 0, stream>>>(h2t, ebuf16, rowpair, inv, bp, out, n);
}